// Round 1
// baseline (11122.738 us; speedup 1.0000x reference)
//
#include <hip/hip_runtime.h>
#include <math.h>

#define B_SZ   2
#define LSEQ   2048
#define DM     1024
#define DI     2048
#define NST    16
#define DTR    64
#define XDBL_N 96
#define NTOK   (B_SZ * LSEQ)
#define NCH    32
#define CS     64
#define EPSF   1e-5f
#define STEPF  0.99f
#define FP_ITERS 8

// ---------------------------------------------------------------------------
// Generic tiled GEMM: C[M,N] = op_epi( op_a(A)[M,K] @ W[N,K]^T )
// AOP: 0 plain A
//      1 A - A2            (A2 stride lda2)
//      2 shift1(A) within each batch of LSEQ rows (row t reads row t-1, t==0 -> 0)
// EOP: 0 C = acc
//      1 C = acc + E[m][n]                       (E stride ldE)
//      2 C = softplus(acc + E[n])                (bias vector)
//      3 C = silu(E[m][n] + acc) * E2[m][n]      (E stride ldE, E2 stride lda2)
// ---------------------------------------------------------------------------
template <int AOP, int EOP>
__global__ __launch_bounds__(256) void gemm_bt(
    const float* __restrict__ A, const float* __restrict__ A2,
    const float* __restrict__ W, const float* __restrict__ E,
    const float* __restrict__ E2, float* __restrict__ C,
    int M, int N, int K, int lda, int lda2, int ldE, int ldc)
{
    __shared__ float As[16][65];
    __shared__ float Ws[16][65];
    const int tid = threadIdx.x;
    const int tx = tid & 15, ty = tid >> 4;
    const int m0 = blockIdx.y * 64, n0 = blockIdx.x * 64;

    float acc[4][4] = {};

    for (int k0 = 0; k0 < K; k0 += 16) {
        #pragma unroll
        for (int i = 0; i < 4; ++i) {
            int e = tid + i * 256;
            int k = e & 15, m = e >> 4;
            int gm = m0 + m, gk = k0 + k;
            float v;
            if (AOP == 0) {
                v = A[(size_t)gm * lda + gk];
            } else if (AOP == 1) {
                v = A[(size_t)gm * lda + gk] - A2[(size_t)gm * lda2 + gk];
            } else {
                int t = gm & (LSEQ - 1);
                v = (t == 0) ? 0.f : A[(size_t)(gm - 1) * lda + gk];
            }
            As[k][m] = v;
        }
        #pragma unroll
        for (int i = 0; i < 4; ++i) {
            int e = tid + i * 256;
            int k = e & 15, n = e >> 4;
            int gn = n0 + n, gk = k0 + k;
            Ws[k][n] = (gn < N) ? W[(size_t)gn * K + gk] : 0.f;
        }
        __syncthreads();
        #pragma unroll
        for (int kk = 0; kk < 16; ++kk) {
            float a[4], w[4];
            #pragma unroll
            for (int i = 0; i < 4; ++i) a[i] = As[kk][ty * 4 + i];
            #pragma unroll
            for (int j = 0; j < 4; ++j) w[j] = Ws[kk][tx * 4 + j];
            #pragma unroll
            for (int i = 0; i < 4; ++i)
                #pragma unroll
                for (int j = 0; j < 4; ++j)
                    acc[i][j] = fmaf(a[i], w[j], acc[i][j]);
        }
        __syncthreads();
    }

    #pragma unroll
    for (int i = 0; i < 4; ++i) {
        int gm = m0 + ty * 4 + i;
        #pragma unroll
        for (int j = 0; j < 4; ++j) {
            int gn = n0 + tx * 4 + j;
            if (gn >= N) continue;
            float v = acc[i][j];
            if (EOP == 1) {
                v += E[(size_t)gm * ldE + gn];
            } else if (EOP == 2) {
                v += E[gn];
                v = (v > 20.f) ? v : log1pf(expf(v));
            } else if (EOP == 3) {
                float z2 = E[(size_t)gm * ldE + gn] + v;
                float s = 1.f / (1.f + __expf(-z2));
                v = z2 * s * E2[(size_t)gm * lda2 + gn];
            }
            C[(size_t)gm * ldc + gn] = v;
        }
    }
}

// ---------------------------------------------------------------------------
// Chunked selective scan.
// h_t[n] = exp(dt_t * A[d][n]) * h_{t-1}[n] + (dt_t*u_t) * B_t[n]
// y_t[d] = sum_n h_t[n]*C_t[n] + D[d]*u_t
// Pass 1: per (b,d,chunk) compute chunk product P[n] and zero-init local h_end[n].
// Pass 2: per (b,d,n) sequential over chunks -> chunk-entry states Hin.
// Pass 3: per (b,d,chunk) redo local scan from Hin, emit y.
// ---------------------------------------------------------------------------
__global__ __launch_bounds__(256) void scan_pass1(
    const float* __restrict__ delta, const float* __restrict__ u,
    const float* __restrict__ Bt, const float* __restrict__ Alog,
    float* __restrict__ Ac, float* __restrict__ Hend)
{
    int d = blockIdx.x * 256 + threadIdx.x;
    int c = blockIdx.y, b = blockIdx.z;
    int t0 = c * CS;
    __shared__ float sB[CS][NST];
    for (int i = threadIdx.x; i < CS * NST; i += 256)
        ((float*)sB)[i] = Bt[(size_t)(b * LSEQ + t0) * NST + i];
    __syncthreads();

    float Avals[NST];
    #pragma unroll
    for (int n = 0; n < NST; ++n) Avals[n] = -__expf(Alog[d * NST + n]);
    float h[NST] = {};
    float P[NST];
    #pragma unroll
    for (int n = 0; n < NST; ++n) P[n] = 1.f;

    const float* dptr = delta + (size_t)(b * LSEQ + t0) * DI + d;
    const float* uptr = u + (size_t)(b * LSEQ + t0) * DI + d;
    for (int tt = 0; tt < CS; ++tt) {
        float dt = dptr[(size_t)tt * DI];
        float ut = uptr[(size_t)tt * DI];
        float w = dt * ut;
        #pragma unroll
        for (int n = 0; n < NST; ++n) {
            float a = __expf(dt * Avals[n]);
            P[n] *= a;
            h[n] = fmaf(a, h[n], w * sB[tt][n]);
        }
    }
    size_t o = ((size_t)((b * NCH + c) * DI) + d) * NST;
    #pragma unroll
    for (int n = 0; n < NST; ++n) { Ac[o + n] = P[n]; Hend[o + n] = h[n]; }
}

__global__ __launch_bounds__(256) void scan_pass2(
    const float* __restrict__ Ac, const float* __restrict__ Hend,
    float* __restrict__ Hin)
{
    int idx = blockIdx.x * 256 + threadIdx.x; // [0, B_SZ*DI*NST)
    int b = idx / (DI * NST);
    int dn = idx % (DI * NST);
    float h = 0.f;
    for (int c = 0; c < NCH; ++c) {
        size_t o = (size_t)(b * NCH + c) * DI * NST + dn;
        Hin[o] = h;
        h = fmaf(Ac[o], h, Hend[o]);
    }
}

__global__ __launch_bounds__(256) void scan_pass3(
    const float* __restrict__ delta, const float* u,
    const float* __restrict__ Bt, const float* __restrict__ Ct,
    const float* __restrict__ Alog, const float* __restrict__ Dp,
    const float* __restrict__ Hin, float* yraw)  // yraw may alias u
{
    int d = blockIdx.x * 256 + threadIdx.x;
    int c = blockIdx.y, b = blockIdx.z;
    int t0 = c * CS;
    __shared__ float sB[CS][NST];
    __shared__ float sC[CS][NST];
    for (int i = threadIdx.x; i < CS * NST; i += 256) {
        ((float*)sB)[i] = Bt[(size_t)(b * LSEQ + t0) * NST + i];
        ((float*)sC)[i] = Ct[(size_t)(b * LSEQ + t0) * NST + i];
    }
    __syncthreads();

    float Avals[NST];
    #pragma unroll
    for (int n = 0; n < NST; ++n) Avals[n] = -__expf(Alog[d * NST + n]);
    float h[NST];
    size_t o = ((size_t)((b * NCH + c) * DI) + d) * NST;
    #pragma unroll
    for (int n = 0; n < NST; ++n) h[n] = Hin[o + n];
    float Dd = Dp[d];

    const float* dptr = delta + (size_t)(b * LSEQ + t0) * DI + d;
    const float* uptr = u + (size_t)(b * LSEQ + t0) * DI + d;
    float* yptr = yraw + (size_t)(b * LSEQ + t0) * DI + d;
    for (int tt = 0; tt < CS; ++tt) {
        float dt = dptr[(size_t)tt * DI];
        float ut = uptr[(size_t)tt * DI];
        float w = dt * ut;
        float acc = 0.f;
        #pragma unroll
        for (int n = 0; n < NST; ++n) {
            float a = __expf(dt * Avals[n]);
            h[n] = fmaf(a, h[n], w * sB[tt][n]);
            acc = fmaf(h[n], sC[tt][n], acc);
        }
        yptr[(size_t)tt * DI] = fmaf(Dd, ut, acc);
    }
}

// ---------------------------------------------------------------------------
// Per-token: layer_norm(yraw) -> fp update -> write ynext; then compute
// bc = ynext @ W_bc^T and produce normalized Bt/Ct for token t+1.
// ---------------------------------------------------------------------------
__global__ __launch_bounds__(256) void ln_update_bc(
    const float* __restrict__ yraw, const float* __restrict__ yprev,
    const float* __restrict__ gamma, const float* __restrict__ beta,
    const float* __restrict__ xdbl, const float* __restrict__ Wbc,
    float* __restrict__ ynext, float* __restrict__ Btb, float* __restrict__ Ctb,
    int is_final)
{
    int t = blockIdx.x, b = blockIdx.y;
    int tid = threadIdx.x;
    const float* yr = yraw + (size_t)(b * LSEQ + t) * DI;
    const float* yp = yprev + (size_t)(b * LSEQ + t) * DI;

    float s = 0.f, s2 = 0.f;
    float vloc[DI / 256];
    #pragma unroll
    for (int i = 0; i < DI / 256; ++i) {
        float v = yr[tid + i * 256];
        vloc[i] = v; s += v; s2 += v * v;
    }
    #pragma unroll
    for (int off = 32; off >= 1; off >>= 1) {
        s += __shfl_down(s, off, 64);
        s2 += __shfl_down(s2, off, 64);
    }
    __shared__ float rs[4], rs2[4];
    __shared__ float smean, srstd;
    int wid = tid >> 6, lane = tid & 63;
    if (lane == 0) { rs[wid] = s; rs2[wid] = s2; }
    __syncthreads();
    if (tid == 0) {
        float S = rs[0] + rs[1] + rs[2] + rs[3];
        float S2 = rs2[0] + rs2[1] + rs2[2] + rs2[3];
        float m = S / (float)DI;
        float var = S2 / (float)DI - m * m;
        smean = m;
        srstd = rsqrtf(var + EPSF);
    }
    __syncthreads();
    float m = smean, r = srstd;

    __shared__ __align__(16) float srow[DI];
    #pragma unroll
    for (int i = 0; i < DI / 256; ++i) {
        int idx = tid + i * 256;
        float ln = (vloc[i] - m) * r * gamma[idx] + beta[idx];
        float yn = is_final ? ln : fmaf(STEPF, ln - yp[idx], yp[idx]);
        ynext[(size_t)(b * LSEQ + t) * DI + idx] = yn;
        srow[idx] = yn;
    }
    __syncthreads();

    // bc[col] = sum_k ynext[k] * Wbc[col][k]   (32 cols, groups of 8 threads)
    int col = tid >> 3, part = tid & 7;
    const float* w = Wbc + (size_t)col * DI;
    float partial = 0.f;
    for (int k4 = part * 4; k4 < DI; k4 += 32) {
        float4 wv = *(const float4*)(w + k4);
        float4 yv = *(const float4*)(srow + k4);
        partial += wv.x * yv.x + wv.y * yv.y + wv.z * yv.z + wv.w * yv.w;
    }
    #pragma unroll
    for (int off = 4; off >= 1; off >>= 1) partial += __shfl_down(partial, off, 8);
    __shared__ float sbc[32];
    if (part == 0) sbc[col] = partial;
    __syncthreads();

    __shared__ float sv[32];
    int tn = t + 1;
    if (tid < 32) {
        float base = (tn < LSEQ) ? xdbl[(size_t)(b * LSEQ + tn) * XDBL_N + DTR + tid] : 0.f;
        sv[tid] = base + sbc[tid];
    }
    __syncthreads();
    if (tid < 32 && tn < LSEQ) {
        int half = tid >> 4;
        float nrm = 0.f;
        #pragma unroll
        for (int j = 0; j < NST; ++j) { float vv = sv[half * NST + j]; nrm += vv * vv; }
        nrm = fmaxf(sqrtf(nrm), EPSF);
        float outv = sv[tid] / nrm;
        float* dst = half ? Ctb : Btb;
        dst[(size_t)(b * LSEQ + tn) * NST + (tid & 15)] = outv;
    }
}

// Bt/Ct for y_prev == 0 (all tokens): normalize(B0), normalize(C0).
__global__ __launch_bounds__(256) void bc_init(
    const float* __restrict__ xdbl, float* __restrict__ Btb, float* __restrict__ Ctb)
{
    int tok = blockIdx.x * 8 + (threadIdx.x >> 5);
    int i = threadIdx.x & 31;
    float v = xdbl[(size_t)tok * XDBL_N + DTR + i];
    float sq = v * v;
    #pragma unroll
    for (int off = 8; off >= 1; off >>= 1) sq += __shfl_xor(sq, off, 16);
    float nrm = fmaxf(sqrtf(sq), EPSF);
    float outv = v / nrm;
    if (i < 16) Btb[(size_t)tok * NST + i] = outv;
    else        Ctb[(size_t)tok * NST + (i - 16)] = outv;
}

__global__ __launch_bounds__(256) void fill_zero(float* p, size_t n)
{
    size_t i = (size_t)blockIdx.x * blockDim.x + threadIdx.x;
    size_t stride = (size_t)gridDim.x * blockDim.x;
    for (; i < n; i += stride) p[i] = 0.f;
}

// ---------------------------------------------------------------------------
extern "C" void kernel_launch(void* const* d_in, const int* in_sizes, int n_in,
                              void* d_out, int out_size, void* d_ws, size_t ws_size,
                              hipStream_t stream)
{
    const float* hs    = (const float*)d_in[0];
    const float* W_in  = (const float*)d_in[1];
    const float* W_x   = (const float*)d_in[2];
    const float* W_dt  = (const float*)d_in[3];
    const float* b_dt  = (const float*)d_in[4];
    const float* A_log = (const float*)d_in[5];
    const float* W_bc  = (const float*)d_in[6];
    const float* W_zy  = (const float*)d_in[7];
    const float* W_mix = (const float*)d_in[8];
    const float* Dp    = (const float*)d_in[9];
    const float* g_ln  = (const float*)d_in[10];
    const float* b_ln  = (const float*)d_in[11];
    const float* W_out = (const float*)d_in[12];
    float* out = (float*)d_out;

    char* ws = (char*)d_ws;
    size_t off = 0;
    auto alloc = [&](size_t bytes) {
        float* p = (float*)(ws + off);
        off += (bytes + 255) & ~(size_t)255;
        return p;
    };
    float* xz    = alloc((size_t)NTOK * (2 * DI) * 4);      // 64 MB: [x | z], ld 4096
    float* xdbl  = alloc((size_t)NTOK * XDBL_N * 4);        // 1.5 MB
    float* delta = alloc((size_t)NTOK * DI * 4);            // 32 MB
    float* ubuf  = alloc((size_t)NTOK * DI * 4);            // 32 MB (x_tilde, aliased by yraw)
    float* yA    = alloc((size_t)NTOK * DI * 4);            // 32 MB
    float* yB    = alloc((size_t)NTOK * DI * 4);            // 32 MB
    float* Btb   = alloc((size_t)NTOK * NST * 4);
    float* Ctb   = alloc((size_t)NTOK * NST * 4);
    float* Ac    = alloc((size_t)B_SZ * NCH * DI * NST * 4);
    float* Hend  = alloc((size_t)B_SZ * NCH * DI * NST * 4);
    float* Hin   = alloc((size_t)B_SZ * NCH * DI * NST * 4);

    float* x = xz;          // stride 4096
    float* z = xz + DI;     // stride 4096
    float* yraw = ubuf;     // alias: pass3 reads u[t][d] before writing y[t][d]

    dim3 blk(256);

    fill_zero<<<1024, 256, 0, stream>>>(yA, (size_t)NTOK * DI);

    // xz = hs @ W_in^T
    gemm_bt<0, 0><<<dim3((2 * DI) / 64, NTOK / 64), blk, 0, stream>>>(
        hs, nullptr, W_in, nullptr, nullptr, xz, NTOK, 2 * DI, DM, DM, 0, 0, 2 * DI);
    // xdbl = x @ W_x^T  (N=96 needs guards)
    gemm_bt<0, 0><<<dim3(2, NTOK / 64), blk, 0, stream>>>(
        x, nullptr, W_x, nullptr, nullptr, xdbl, NTOK, XDBL_N, DI, 2 * DI, 0, 0, XDBL_N);
    // delta = softplus(dt_low @ W_dt^T + b_dt)
    gemm_bt<0, 2><<<dim3(DI / 64, NTOK / 64), blk, 0, stream>>>(
        xdbl, nullptr, W_dt, b_dt, nullptr, delta, NTOK, DI, DTR, XDBL_N, 0, 0, DI);
    // Bt/Ct for y_prev = 0
    bc_init<<<NTOK / 8, 256, 0, stream>>>(xdbl, Btb, Ctb);

    float* ycur = yA;
    float* ynext = yB;
    for (int it = 0; it <= FP_ITERS; ++it) {
        // u = (x - ycur) @ W_mix^T + ycur
        gemm_bt<1, 1><<<dim3(DI / 64, NTOK / 64), blk, 0, stream>>>(
            x, ycur, W_mix, ycur, nullptr, ubuf, NTOK, DI, DI, 2 * DI, DI, DI, DI);
        scan_pass1<<<dim3(DI / 256, NCH, B_SZ), blk, 0, stream>>>(
            delta, ubuf, Btb, A_log, Ac, Hend);
        scan_pass2<<<dim3(B_SZ * DI * NST / 256), blk, 0, stream>>>(Ac, Hend, Hin);
        scan_pass3<<<dim3(DI / 256, NCH, B_SZ), blk, 0, stream>>>(
            delta, ubuf, Btb, Ctb, A_log, Dp, Hin, yraw);
        ln_update_bc<<<dim3(LSEQ, B_SZ), blk, 0, stream>>>(
            yraw, ycur, g_ln, b_ln, xdbl, W_bc, ynext, Btb, Ctb, it == FP_ITERS ? 1 : 0);
        float* tmp = ycur; ycur = ynext; ynext = tmp;
    }

    // g = silu(z + shift1(y) @ W_zy^T) * y   -> yraw (ubuf free now)
    gemm_bt<2, 3><<<dim3(DI / 64, NTOK / 64), blk, 0, stream>>>(
        ycur, ycur, W_zy, z, ycur, yraw, NTOK, DI, DI, DI, DI, 2 * DI, DI);
    // out = g @ W_out^T
    gemm_bt<0, 0><<<dim3(DM / 64, NTOK / 64), blk, 0, stream>>>(
        yraw, nullptr, W_out, nullptr, nullptr, out, NTOK, DM, DI, DI, 0, 0, DM);
}

// Round 2
// 3681.937 us; speedup vs baseline: 3.0209x; 3.0209x over previous
//
#include <hip/hip_runtime.h>
#include <math.h>

#define B_SZ   2
#define LSEQ   2048
#define DM     1024
#define DI     2048
#define NST    16
#define DTR    64
#define XDBL_N 96
#define NTOK   (B_SZ * LSEQ)
#define NCH    32
#define CS     64
#define EPSF   1e-5f
#define STEPF  0.99f
#define FP_ITERS 8

typedef __attribute__((ext_vector_type(8))) short bf16x8;
typedef __attribute__((ext_vector_type(4))) float f32x4;
typedef unsigned short ushort_t;

__device__ __forceinline__ ushort_t f2bf(float v) {
    unsigned u = __float_as_uint(v);
    unsigned r = (u + 0x7fffu + ((u >> 16) & 1u)) >> 16;   // RNE
    return (ushort_t)r;
}
__device__ __forceinline__ float bf2f(ushort_t h) {
    return __uint_as_float(((unsigned)h) << 16);
}
__device__ __forceinline__ void split1(float v, ushort_t& h, ushort_t& l) {
    h = f2bf(v);
    l = f2bf(v - bf2f(h));
}
__device__ __forceinline__ void load_lds16(const void* g, void* l) {
    __builtin_amdgcn_global_load_lds(
        (const __attribute__((address_space(1))) unsigned int*)g,
        (__attribute__((address_space(3))) unsigned int*)l, 16, 0, 0);
}

// ---------------------------------------------------------------------------
// fp32 tiled GEMM (kept for xz / xdbl / delta — the accuracy-critical path).
// AOP: 0 plain; EOP: 0 plain, 2 softplus(acc + bias[n])
// ---------------------------------------------------------------------------
template <int AOP, int EOP>
__global__ __launch_bounds__(256) void gemm_bt(
    const float* __restrict__ A, const float* __restrict__ A2,
    const float* __restrict__ W, const float* __restrict__ E,
    const float* __restrict__ E2, float* __restrict__ C,
    int M, int N, int K, int lda, int lda2, int ldE, int ldc)
{
    __shared__ float As[16][65];
    __shared__ float Ws[16][65];
    const int tid = threadIdx.x;
    const int tx = tid & 15, ty = tid >> 4;
    const int m0 = blockIdx.y * 64, n0 = blockIdx.x * 64;

    float acc[4][4] = {};

    for (int k0 = 0; k0 < K; k0 += 16) {
        #pragma unroll
        for (int i = 0; i < 4; ++i) {
            int e = tid + i * 256;
            int k = e & 15, m = e >> 4;
            int gm = m0 + m, gk = k0 + k;
            As[k][m] = A[(size_t)gm * lda + gk];
        }
        #pragma unroll
        for (int i = 0; i < 4; ++i) {
            int e = tid + i * 256;
            int k = e & 15, n = e >> 4;
            int gn = n0 + n, gk = k0 + k;
            Ws[k][n] = (gn < N) ? W[(size_t)gn * K + gk] : 0.f;
        }
        __syncthreads();
        #pragma unroll
        for (int kk = 0; kk < 16; ++kk) {
            float a[4], w[4];
            #pragma unroll
            for (int i = 0; i < 4; ++i) a[i] = As[kk][ty * 4 + i];
            #pragma unroll
            for (int j = 0; j < 4; ++j) w[j] = Ws[kk][tx * 4 + j];
            #pragma unroll
            for (int i = 0; i < 4; ++i)
                #pragma unroll
                for (int j = 0; j < 4; ++j)
                    acc[i][j] = fmaf(a[i], w[j], acc[i][j]);
        }
        __syncthreads();
    }

    #pragma unroll
    for (int i = 0; i < 4; ++i) {
        int gm = m0 + ty * 4 + i;
        #pragma unroll
        for (int j = 0; j < 4; ++j) {
            int gn = n0 + tx * 4 + j;
            if (gn >= N) continue;
            float v = acc[i][j];
            if (EOP == 2) {
                v += E[gn];
                v = (v > 20.f) ? v : log1pf(expf(v));
            }
            C[(size_t)gm * ldc + gn] = v;
        }
    }
}

// ---------------------------------------------------------------------------
// Split fp32 -> bf16 hi/lo pair.
// MODE 0: A          (lda)
// MODE 1: A - S      (A stride lda, S stride K)
// MODE 2: shift1(A)  (A stride lda; row t reads t-1 within each LSEQ batch)
// Output dense [M][K] bf16.
// ---------------------------------------------------------------------------
template <int MODE>
__global__ __launch_bounds__(256) void split_bf16(
    const float* __restrict__ A, const float* __restrict__ S,
    ushort_t* __restrict__ Hi, ushort_t* __restrict__ Lo,
    int M, int K, int lda)
{
    int K4 = K >> 2;
    long total = (long)M * K4;
    for (long i = (long)blockIdx.x * 256 + threadIdx.x; i < total;
         i += (long)gridDim.x * 256) {
        int m = (int)(i / K4);
        int k = (int)(i - (long)m * K4) * 4;
        float4 a;
        if (MODE == 2) {
            int t = m & (LSEQ - 1);
            if (t == 0) a = make_float4(0.f, 0.f, 0.f, 0.f);
            else        a = *(const float4*)(A + (size_t)(m - 1) * lda + k);
        } else {
            a = *(const float4*)(A + (size_t)m * lda + k);
            if (MODE == 1) {
                float4 s4 = *(const float4*)(S + (size_t)m * K + k);
                a.x -= s4.x; a.y -= s4.y; a.z -= s4.z; a.w -= s4.w;
            }
        }
        ushort4 hv, lv;
        split1(a.x, hv.x, lv.x);
        split1(a.y, hv.y, lv.y);
        split1(a.z, hv.z, lv.z);
        split1(a.w, hv.w, lv.w);
        *(ushort4*)(Hi + (size_t)m * K + k) = hv;
        *(ushort4*)(Lo + (size_t)m * K + k) = lv;
    }
}

// ---------------------------------------------------------------------------
// Split-bf16 MFMA GEMM: C[m][n] = epi( sum_k A[m,k]*W[n,k] ), A ~= Ahi+Alo,
// W ~= Whi+Wlo, 3 MFMA products (hh, hl, lh) per fragment pair, fp32 acc.
// 128x128 tile, BK=32, 256 threads = 4 waves (2x2 of 64x64), global_load_lds.
// M,N multiples of 128; K multiple of 32.
// EOP: 0 C = acc
//      1 C = acc + E[m][n]                        (x_tilde)
//      3 g = silu(E[m][n]+acc) * E2[m][n]; write bf16 split to Chi/Clo
// ---------------------------------------------------------------------------
template <int EOP>
__global__ __launch_bounds__(256) void mfma_gemm(
    const ushort_t* __restrict__ Ahi, const ushort_t* __restrict__ Alo,
    const ushort_t* __restrict__ Whi, const ushort_t* __restrict__ Wlo,
    const float* __restrict__ E, const float* __restrict__ E2,
    float* __restrict__ C, ushort_t* __restrict__ Chi, ushort_t* __restrict__ Clo,
    int M, int N, int K, int ldE, int ldE2, int ldc)
{
    __shared__ __align__(16) short lds[16384];  // 32 KB: Ahi|Alo|Whi|Wlo, each 128x32
    short* sAhi = lds;
    short* sAlo = lds + 4096;
    short* sWhi = lds + 8192;
    short* sWlo = lds + 12288;
    char* ldsc = (char*)lds;

    const int tid = threadIdx.x, lane = tid & 63, w = tid >> 6;
    const int m0 = blockIdx.y * 128, n0 = blockIdx.x * 128;
    const int wm = (w & 1) * 64, wn = (w >> 1) * 64;

    f32x4 zero4 = {0.f, 0.f, 0.f, 0.f};
    f32x4 acc[4][4];
    #pragma unroll
    for (int mi = 0; mi < 4; ++mi)
        #pragma unroll
        for (int ni = 0; ni < 4; ++ni) acc[mi][ni] = zero4;

    // staging addresses: issue j = w*2+i covers bytes [j*1024, +1024) of each
    // 8 KB buffer; lane covers 16 B at row j*16 + lane/4, k-elem (lane&3)*8
    size_t aoff[2], woff[2];
    #pragma unroll
    for (int i = 0; i < 2; ++i) {
        int j = w * 2 + i;
        int row = j * 16 + (lane >> 2);
        int ke = (lane & 3) * 8;
        aoff[i] = (size_t)(m0 + row) * K + ke;
        woff[i] = (size_t)(n0 + row) * K + ke;
    }
    // fragment read offsets (elements), mi/ni add 16*32
    const int abase = (wm + (lane & 15)) * 32 + (lane >> 4) * 8;
    const int bbase = (wn + (lane & 15)) * 32 + (lane >> 4) * 8;

    for (int k0 = 0; k0 < K; k0 += 32) {
        #pragma unroll
        for (int i = 0; i < 2; ++i) {
            int dst = (w * 2 + i) * 1024;
            load_lds16(Ahi + aoff[i], ldsc + dst);
            load_lds16(Alo + aoff[i], ldsc + 8192 + dst);
            load_lds16(Whi + woff[i], ldsc + 16384 + dst);
            load_lds16(Wlo + woff[i], ldsc + 24576 + dst);
            aoff[i] += 32; woff[i] += 32;
        }
        __syncthreads();

        bf16x8 ah[4], al[4], bh[4], bl[4];
        #pragma unroll
        for (int mi = 0; mi < 4; ++mi) {
            ah[mi] = *(const bf16x8*)(sAhi + abase + mi * 512);
            al[mi] = *(const bf16x8*)(sAlo + abase + mi * 512);
        }
        #pragma unroll
        for (int ni = 0; ni < 4; ++ni) {
            bh[ni] = *(const bf16x8*)(sWhi + bbase + ni * 512);
            bl[ni] = *(const bf16x8*)(sWlo + bbase + ni * 512);
        }
        #pragma unroll
        for (int mi = 0; mi < 4; ++mi)
            #pragma unroll
            for (int ni = 0; ni < 4; ++ni) {
                acc[mi][ni] = __builtin_amdgcn_mfma_f32_16x16x32_bf16(ah[mi], bh[ni], acc[mi][ni], 0, 0, 0);
                acc[mi][ni] = __builtin_amdgcn_mfma_f32_16x16x32_bf16(ah[mi], bl[ni], acc[mi][ni], 0, 0, 0);
                acc[mi][ni] = __builtin_amdgcn_mfma_f32_16x16x32_bf16(al[mi], bh[ni], acc[mi][ni], 0, 0, 0);
            }
        __syncthreads();
    }

    // C/D layout: col = lane&15, row = (lane>>4)*4 + reg
    const int col = lane & 15, rb = (lane >> 4) * 4;
    #pragma unroll
    for (int mi = 0; mi < 4; ++mi) {
        #pragma unroll
        for (int r = 0; r < 4; ++r) {
            int gm = m0 + wm + mi * 16 + rb + r;
            #pragma unroll
            for (int ni = 0; ni < 4; ++ni) {
                int gn = n0 + wn + ni * 16 + col;
                float v = acc[mi][ni][r];
                if (EOP == 1) v += E[(size_t)gm * ldE + gn];
                if (EOP == 0 || EOP == 1) {
                    C[(size_t)gm * ldc + gn] = v;
                } else {
                    float z2 = E[(size_t)gm * ldE + gn] + v;
                    float s = 1.f / (1.f + __expf(-z2));
                    float g = z2 * s * E2[(size_t)gm * ldE2 + gn];
                    ushort_t h, l;
                    split1(g, h, l);
                    Chi[(size_t)gm * ldc + gn] = h;
                    Clo[(size_t)gm * ldc + gn] = l;
                }
            }
        }
    }
}

// ---------------------------------------------------------------------------
// Chunked selective scan (unchanged except pass2 writes Hin in place of Ac).
// ---------------------------------------------------------------------------
__global__ __launch_bounds__(256) void scan_pass1(
    const float* __restrict__ delta, const float* __restrict__ u,
    const float* __restrict__ Bt, const float* __restrict__ Alog,
    float* __restrict__ Ac, float* __restrict__ Hend)
{
    int d = blockIdx.x * 256 + threadIdx.x;
    int c = blockIdx.y, b = blockIdx.z;
    int t0 = c * CS;
    __shared__ float sB[CS][NST];
    for (int i = threadIdx.x; i < CS * NST; i += 256)
        ((float*)sB)[i] = Bt[(size_t)(b * LSEQ + t0) * NST + i];
    __syncthreads();

    float Avals[NST];
    #pragma unroll
    for (int n = 0; n < NST; ++n) Avals[n] = -__expf(Alog[d * NST + n]);
    float h[NST] = {};
    float P[NST];
    #pragma unroll
    for (int n = 0; n < NST; ++n) P[n] = 1.f;

    const float* dptr = delta + (size_t)(b * LSEQ + t0) * DI + d;
    const float* uptr = u + (size_t)(b * LSEQ + t0) * DI + d;
    for (int tt = 0; tt < CS; ++tt) {
        float dt = dptr[(size_t)tt * DI];
        float ut = uptr[(size_t)tt * DI];
        float wv = dt * ut;
        #pragma unroll
        for (int n = 0; n < NST; ++n) {
            float a = __expf(dt * Avals[n]);
            P[n] *= a;
            h[n] = fmaf(a, h[n], wv * sB[tt][n]);
        }
    }
    size_t o = ((size_t)((b * NCH + c) * DI) + d) * NST;
    #pragma unroll
    for (int n = 0; n < NST; ++n) { Ac[o + n] = P[n]; Hend[o + n] = h[n]; }
}

__global__ __launch_bounds__(256) void scan_pass2(
    float* __restrict__ Ac, const float* __restrict__ Hend)
{
    int idx = blockIdx.x * 256 + threadIdx.x;
    int b = idx / (DI * NST);
    int dn = idx % (DI * NST);
    float h = 0.f;
    for (int c = 0; c < NCH; ++c) {
        size_t o = (size_t)(b * NCH + c) * DI * NST + dn;
        float a = Ac[o];
        float e = Hend[o];
        Ac[o] = h;               // Hin in place
        h = fmaf(a, h, e);
    }
}

__global__ __launch_bounds__(256) void scan_pass3(
    const float* __restrict__ delta, const float* u,
    const float* __restrict__ Bt, const float* __restrict__ Ct,
    const float* __restrict__ Alog, const float* __restrict__ Dp,
    const float* __restrict__ Hin, float* yraw)  // yraw aliases u
{
    int d = blockIdx.x * 256 + threadIdx.x;
    int c = blockIdx.y, b = blockIdx.z;
    int t0 = c * CS;
    __shared__ float sB[CS][NST];
    __shared__ float sC[CS][NST];
    for (int i = threadIdx.x; i < CS * NST; i += 256) {
        ((float*)sB)[i] = Bt[(size_t)(b * LSEQ + t0) * NST + i];
        ((float*)sC)[i] = Ct[(size_t)(b * LSEQ + t0) * NST + i];
    }
    __syncthreads();

    float Avals[NST];
    #pragma unroll
    for (int n = 0; n < NST; ++n) Avals[n] = -__expf(Alog[d * NST + n]);
    float h[NST];
    size_t o = ((size_t)((b * NCH + c) * DI) + d) * NST;
    #pragma unroll
    for (int n = 0; n < NST; ++n) h[n] = Hin[o + n];
    float Dd = Dp[d];

    const float* dptr = delta + (size_t)(b * LSEQ + t0) * DI + d;
    const float* uptr = u + (size_t)(b * LSEQ + t0) * DI + d;
    float* yptr = yraw + (size_t)(b * LSEQ + t0) * DI + d;
    for (int tt = 0; tt < CS; ++tt) {
        float dt = dptr[(size_t)tt * DI];
        float ut = uptr[(size_t)tt * DI];
        float wv = dt * ut;
        float acc = 0.f;
        #pragma unroll
        for (int n = 0; n < NST; ++n) {
            float a = __expf(dt * Avals[n]);
            h[n] = fmaf(a, h[n], wv * sB[tt][n]);
            acc = fmaf(h[n], sC[tt][n], acc);
        }
        yptr[(size_t)tt * DI] = fmaf(Dd, ut, acc);
    }
}

// ---------------------------------------------------------------------------
// Per-token LN -> fp update (in place) -> Bt/Ct for token t+1.
// ---------------------------------------------------------------------------
__global__ __launch_bounds__(256) void ln_update_bc(
    const float* __restrict__ yraw, float* __restrict__ ybuf,
    const float* __restrict__ gamma, const float* __restrict__ beta,
    const float* __restrict__ xdbl, const float* __restrict__ Wbc,
    float* __restrict__ Btb, float* __restrict__ Ctb,
    int is_final)
{
    int t = blockIdx.x, b = blockIdx.y;
    int tid = threadIdx.x;
    const float* yr = yraw + (size_t)(b * LSEQ + t) * DI;
    float* yp = ybuf + (size_t)(b * LSEQ + t) * DI;

    float s = 0.f, s2 = 0.f;
    float vloc[DI / 256];
    #pragma unroll
    for (int i = 0; i < DI / 256; ++i) {
        float v = yr[tid + i * 256];
        vloc[i] = v; s += v; s2 += v * v;
    }
    #pragma unroll
    for (int off = 32; off >= 1; off >>= 1) {
        s += __shfl_down(s, off, 64);
        s2 += __shfl_down(s2, off, 64);
    }
    __shared__ float rs[4], rs2[4];
    __shared__ float smean, srstd;
    int wid = tid >> 6, lane = tid & 63;
    if (lane == 0) { rs[wid] = s; rs2[wid] = s2; }
    __syncthreads();
    if (tid == 0) {
        float S = rs[0] + rs[1] + rs[2] + rs[3];
        float S2 = rs2[0] + rs2[1] + rs2[2] + rs2[3];
        float m = S / (float)DI;
        float var = S2 / (float)DI - m * m;
        smean = m;
        srstd = rsqrtf(var + EPSF);
    }
    __syncthreads();
    float m = smean, r = srstd;

    __shared__ __align__(16) float srow[DI];
    #pragma unroll
    for (int i = 0; i < DI / 256; ++i) {
        int idx = tid + i * 256;
        float ln = (vloc[i] - m) * r * gamma[idx] + beta[idx];
        float yn = is_final ? ln : fmaf(STEPF, ln - yp[idx], yp[idx]);
        yp[idx] = yn;
        srow[idx] = yn;
    }
    __syncthreads();

    int colc = tid >> 3, part = tid & 7;
    const float* wv = Wbc + (size_t)colc * DI;
    float partial = 0.f;
    for (int k4 = part * 4; k4 < DI; k4 += 32) {
        float4 w4 = *(const float4*)(wv + k4);
        float4 y4 = *(const float4*)(srow + k4);
        partial += w4.x * y4.x + w4.y * y4.y + w4.z * y4.z + w4.w * y4.w;
    }
    #pragma unroll
    for (int off = 4; off >= 1; off >>= 1) partial += __shfl_down(partial, off, 8);
    __shared__ float sbc[32];
    if (part == 0) sbc[colc] = partial;
    __syncthreads();

    __shared__ float sv[32];
    int tn = t + 1;
    if (tid < 32) {
        float base = (tn < LSEQ) ? xdbl[(size_t)(b * LSEQ + tn) * XDBL_N + DTR + tid] : 0.f;
        sv[tid] = base + sbc[tid];
    }
    __syncthreads();
    if (tid < 32 && tn < LSEQ) {
        int half = tid >> 4;
        float nrm = 0.f;
        #pragma unroll
        for (int j = 0; j < NST; ++j) { float vv = sv[half * NST + j]; nrm += vv * vv; }
        nrm = fmaxf(sqrtf(nrm), EPSF);
        float outv = sv[tid] / nrm;
        float* dst = half ? Ctb : Btb;
        dst[(size_t)(b * LSEQ + tn) * NST + (tid & 15)] = outv;
    }
}

__global__ __launch_bounds__(256) void bc_init(
    const float* __restrict__ xdbl, float* __restrict__ Btb, float* __restrict__ Ctb)
{
    int tok = blockIdx.x * 8 + (threadIdx.x >> 5);
    int i = threadIdx.x & 31;
    float v = xdbl[(size_t)tok * XDBL_N + DTR + i];
    float sq = v * v;
    #pragma unroll
    for (int off = 8; off >= 1; off >>= 1) sq += __shfl_xor(sq, off, 16);
    float nrm = fmaxf(sqrtf(sq), EPSF);
    float outv = v / nrm;
    if (i < 16) Btb[(size_t)tok * NST + i] = outv;
    else        Ctb[(size_t)tok * NST + (i - 16)] = outv;
}

__global__ __launch_bounds__(256) void fill_zero(float* p, size_t n)
{
    size_t i = (size_t)blockIdx.x * blockDim.x + threadIdx.x;
    size_t stride = (size_t)gridDim.x * blockDim.x;
    for (; i < n; i += stride) p[i] = 0.f;
}

// ---------------------------------------------------------------------------
extern "C" void kernel_launch(void* const* d_in, const int* in_sizes, int n_in,
                              void* d_out, int out_size, void* d_ws, size_t ws_size,
                              hipStream_t stream)
{
    const float* hs    = (const float*)d_in[0];
    const float* W_in  = (const float*)d_in[1];
    const float* W_x   = (const float*)d_in[2];
    const float* W_dt  = (const float*)d_in[3];
    const float* b_dt  = (const float*)d_in[4];
    const float* A_log = (const float*)d_in[5];
    const float* W_bc  = (const float*)d_in[6];
    const float* W_zy  = (const float*)d_in[7];
    const float* W_mix = (const float*)d_in[8];
    const float* Dp    = (const float*)d_in[9];
    const float* g_ln  = (const float*)d_in[10];
    const float* b_ln  = (const float*)d_in[11];
    const float* W_out = (const float*)d_in[12];
    float* out = (float*)d_out;

    char* ws = (char*)d_ws;
    size_t off = 0;
    auto alloc = [&](size_t bytes) {
        void* p = (void*)(ws + off);
        off += (bytes + 255) & ~(size_t)255;
        return p;
    };
    float*   xz    = (float*)alloc((size_t)NTOK * (2 * DI) * 4);  // [x | z], ld 4096
    float*   xdbl  = (float*)alloc((size_t)NTOK * XDBL_N * 4);
    float*   delta = (float*)alloc((size_t)NTOK * DI * 4);        // later: Ghi|Glo
    float*   ubuf  = (float*)alloc((size_t)NTOK * DI * 4);        // x_tilde / yraw
    float*   yA    = (float*)alloc((size_t)NTOK * DI * 4);        // y (in-place)
    float*   Btb   = (float*)alloc((size_t)NTOK * NST * 4);
    float*   Ctb   = (float*)alloc((size_t)NTOK * NST * 4);
    float*   Ac    = (float*)alloc((size_t)B_SZ * NCH * DI * NST * 4); // + Hin alias, + Wzy/Wout hi
    float*   Hend  = (float*)alloc((size_t)B_SZ * NCH * DI * NST * 4); // + Wzy/Wout lo
    ushort_t* Ahi  = (ushort_t*)alloc((size_t)NTOK * DI * 2);
    ushort_t* Alo  = (ushort_t*)alloc((size_t)NTOK * DI * 2);
    ushort_t* WmixHi = (ushort_t*)alloc((size_t)DI * DI * 2);
    ushort_t* WmixLo = (ushort_t*)alloc((size_t)DI * DI * 2);

    float* x = xz;
    float* z = xz + DI;
    float* yraw = ubuf;
    ushort_t* Ghi = (ushort_t*)delta;              // after last scan, delta is free
    ushort_t* Glo = Ghi + (size_t)NTOK * DI;
    ushort_t* WzyHi = (ushort_t*)Ac;               // after scans
    ushort_t* WzyLo = (ushort_t*)Hend;

    dim3 blk(256);

    fill_zero<<<1024, 256, 0, stream>>>(yA, (size_t)NTOK * DI);

    // fp32 path: xz, xdbl, delta (feeds exp/softplus — keep full precision)
    gemm_bt<0, 0><<<dim3((2 * DI) / 64, NTOK / 64), blk, 0, stream>>>(
        hs, nullptr, W_in, nullptr, nullptr, xz, NTOK, 2 * DI, DM, DM, 0, 0, 2 * DI);
    gemm_bt<0, 0><<<dim3(2, NTOK / 64), blk, 0, stream>>>(
        x, nullptr, W_x, nullptr, nullptr, xdbl, NTOK, XDBL_N, DI, 2 * DI, 0, 0, XDBL_N);
    gemm_bt<0, 2><<<dim3(DI / 64, NTOK / 64), blk, 0, stream>>>(
        xdbl, nullptr, W_dt, b_dt, nullptr, delta, NTOK, DI, DTR, XDBL_N, 0, 0, DI);
    bc_init<<<NTOK / 8, 256, 0, stream>>>(xdbl, Btb, Ctb);

    // one-time weight split
    split_bf16<0><<<dim3(4096), blk, 0, stream>>>(W_mix, nullptr, WmixHi, WmixLo, DI, DI, DI);

    for (int it = 0; it <= FP_ITERS; ++it) {
        split_bf16<1><<<dim3(8192), blk, 0, stream>>>(x, yA, Ahi, Alo, NTOK, DI, 2 * DI);
        mfma_gemm<1><<<dim3(DI / 128, NTOK / 128), blk, 0, stream>>>(
            Ahi, Alo, WmixHi, WmixLo, yA, nullptr, ubuf, nullptr, nullptr,
            NTOK, DI, DI, DI, 0, DI);
        scan_pass1<<<dim3(DI / 256, NCH, B_SZ), blk, 0, stream>>>(
            delta, ubuf, Btb, A_log, Ac, Hend);
        scan_pass2<<<dim3(B_SZ * DI * NST / 256), blk, 0, stream>>>(Ac, Hend);
        scan_pass3<<<dim3(DI / 256, NCH, B_SZ), blk, 0, stream>>>(
            delta, ubuf, Btb, Ctb, A_log, Dp, Ac, yraw);
        ln_update_bc<<<dim3(LSEQ, B_SZ), blk, 0, stream>>>(
            yraw, yA, g_ln, b_ln, xdbl, W_bc, Btb, Ctb, it == FP_ITERS ? 1 : 0);
    }

    // g = silu(z + shift1(y) @ W_zy^T) * y  -> bf16 split (Ghi/Glo in delta buf)
    split_bf16<2><<<dim3(8192), blk, 0, stream>>>(yA, nullptr, Ahi, Alo, NTOK, DI, DI);
    split_bf16<0><<<dim3(4096), blk, 0, stream>>>(W_zy, nullptr, WzyHi, WzyLo, DI, DI, DI);
    mfma_gemm<3><<<dim3(DI / 128, NTOK / 128), blk, 0, stream>>>(
        Ahi, Alo, WzyHi, WzyLo, z, yA, nullptr, Ghi, Glo,
        NTOK, DI, DI, 2 * DI, DI, DI);

    // out = g @ W_out^T
    ushort_t* WoutHi = (ushort_t*)Ac;   // reuse after z2 GEMM
    ushort_t* WoutLo = (ushort_t*)Hend;
    split_bf16<0><<<dim3(2048), blk, 0, stream>>>(W_out, nullptr, WoutHi, WoutLo, DM, DI, DI);
    mfma_gemm<0><<<dim3(DM / 128, NTOK / 128), blk, 0, stream>>>(
        Ghi, Glo, WoutHi, WoutLo, nullptr, nullptr, out, nullptr, nullptr,
        NTOK, DM, DI, 0, 0, DM);
}

// Round 3
// 2816.069 us; speedup vs baseline: 3.9497x; 1.3075x over previous
//
#include <hip/hip_runtime.h>
#include <math.h>

#define B_SZ   2
#define LSEQ   2048
#define DM     1024
#define DI     2048
#define NST    16
#define DTR    64
#define XDBL_N 96
#define NTOK   (B_SZ * LSEQ)
#define NCH    32
#define CS     64
#define EPSF   1e-5f
#define STEPF  0.99f
#define FP_ITERS 8

typedef __attribute__((ext_vector_type(8))) short bf16x8;
typedef __attribute__((ext_vector_type(4))) float f32x4;
typedef unsigned short ushort_t;

__device__ __forceinline__ ushort_t f2bf(float v) {
    unsigned u = __float_as_uint(v);
    unsigned r = (u + 0x7fffu + ((u >> 16) & 1u)) >> 16;   // RNE
    return (ushort_t)r;
}
__device__ __forceinline__ float bf2f(ushort_t h) {
    return __uint_as_float(((unsigned)h) << 16);
}
__device__ __forceinline__ void split1(float v, ushort_t& h, ushort_t& l) {
    h = f2bf(v);
    l = f2bf(v - bf2f(h));
}
__device__ __forceinline__ void load_lds16(const void* g, void* l) {
    __builtin_amdgcn_global_load_lds(
        (const __attribute__((address_space(1))) unsigned int*)g,
        (__attribute__((address_space(3))) unsigned int*)l, 16, 0, 0);
}

// ---------------------------------------------------------------------------
// Split fp32 -> bf16 hi/lo pair.
// MODE 0: A plain      (lda)
// MODE 2: shift1(A)    (row t reads t-1 within each LSEQ batch)
// ---------------------------------------------------------------------------
template <int MODE>
__global__ __launch_bounds__(256) void split_bf16(
    const float* __restrict__ A,
    ushort_t* __restrict__ Hi, ushort_t* __restrict__ Lo,
    int M, int K, int lda)
{
    int K4 = K >> 2;
    long total = (long)M * K4;
    for (long i = (long)blockIdx.x * 256 + threadIdx.x; i < total;
         i += (long)gridDim.x * 256) {
        int m = (int)(i / K4);
        int k = (int)(i - (long)m * K4) * 4;
        float4 a;
        if (MODE == 2) {
            int t = m & (LSEQ - 1);
            if (t == 0) a = make_float4(0.f, 0.f, 0.f, 0.f);
            else        a = *(const float4*)(A + (size_t)(m - 1) * lda + k);
        } else {
            a = *(const float4*)(A + (size_t)m * lda + k);
        }
        ushort4 hv, lv;
        split1(a.x, hv.x, lv.x);
        split1(a.y, hv.y, lv.y);
        split1(a.z, hv.z, lv.z);
        split1(a.w, hv.w, lv.w);
        *(ushort4*)(Hi + (size_t)m * K + k) = hv;
        *(ushort4*)(Lo + (size_t)m * K + k) = lv;
    }
}

// ---------------------------------------------------------------------------
// Split-bf16 MFMA GEMM: C[m][n] = epi( sum_k A[m,k]*W[n,k] ), 3 MFMA per
// fragment pair (hh, hl, lh), fp32 acc. 128x128 tile, BK=32, 4 waves.
// Optional split-K via gridDim.z: each z does K/gridDim.z, writes partial
// C + z*M*ldc.
// EOP: 0 C = acc
//      1 C = acc + E[m][n]                        (ldE)
//      2 C = softplus(acc + E2[n])                (bias vector via E2)
//      3 g = silu(E[m][n]+acc) * E2[m][n]; split -> Chi/Clo
//      4 split(acc) -> Chi/Clo
// ---------------------------------------------------------------------------
template <int EOP>
__global__ __launch_bounds__(256) void mfma_gemm(
    const ushort_t* __restrict__ Ahi, const ushort_t* __restrict__ Alo,
    const ushort_t* __restrict__ Whi, const ushort_t* __restrict__ Wlo,
    const float* __restrict__ E, const float* __restrict__ E2,
    float* __restrict__ C, ushort_t* __restrict__ Chi, ushort_t* __restrict__ Clo,
    int M, int N, int K, int ldE, int ldE2, int ldc)
{
    __shared__ __align__(16) short lds[16384];  // 32 KB: Ahi|Alo|Whi|Wlo, each 128x32
    short* sAhi = lds;
    short* sAlo = lds + 4096;
    short* sWhi = lds + 8192;
    short* sWlo = lds + 12288;
    char* ldsc = (char*)lds;

    const int tid = threadIdx.x, lane = tid & 63, w = tid >> 6;
    const int m0 = blockIdx.y * 128, n0 = blockIdx.x * 128;
    const int wm = (w & 1) * 64, wn = (w >> 1) * 64;

    const int ksub = K / gridDim.z;
    const int kbeg = blockIdx.z * ksub;
    if (gridDim.z > 1) C += (size_t)blockIdx.z * M * ldc;

    f32x4 zero4 = {0.f, 0.f, 0.f, 0.f};
    f32x4 acc[4][4];
    #pragma unroll
    for (int mi = 0; mi < 4; ++mi)
        #pragma unroll
        for (int ni = 0; ni < 4; ++ni) acc[mi][ni] = zero4;

    size_t aoff[2], woff[2];
    #pragma unroll
    for (int i = 0; i < 2; ++i) {
        int j = w * 2 + i;
        int row = j * 16 + (lane >> 2);
        int ke = (lane & 3) * 8;
        aoff[i] = (size_t)(m0 + row) * K + kbeg + ke;
        woff[i] = (size_t)(n0 + row) * K + kbeg + ke;
    }
    const int abase = (wm + (lane & 15)) * 32 + (lane >> 4) * 8;
    const int bbase = (wn + (lane & 15)) * 32 + (lane >> 4) * 8;

    for (int k0 = 0; k0 < ksub; k0 += 32) {
        #pragma unroll
        for (int i = 0; i < 2; ++i) {
            int dst = (w * 2 + i) * 1024;
            load_lds16(Ahi + aoff[i], ldsc + dst);
            load_lds16(Alo + aoff[i], ldsc + 8192 + dst);
            load_lds16(Whi + woff[i], ldsc + 16384 + dst);
            load_lds16(Wlo + woff[i], ldsc + 24576 + dst);
            aoff[i] += 32; woff[i] += 32;
        }
        __syncthreads();

        bf16x8 ah[4], al[4], bh[4], bl[4];
        #pragma unroll
        for (int mi = 0; mi < 4; ++mi) {
            ah[mi] = *(const bf16x8*)(sAhi + abase + mi * 512);
            al[mi] = *(const bf16x8*)(sAlo + abase + mi * 512);
        }
        #pragma unroll
        for (int ni = 0; ni < 4; ++ni) {
            bh[ni] = *(const bf16x8*)(sWhi + bbase + ni * 512);
            bl[ni] = *(const bf16x8*)(sWlo + bbase + ni * 512);
        }
        #pragma unroll
        for (int mi = 0; mi < 4; ++mi)
            #pragma unroll
            for (int ni = 0; ni < 4; ++ni) {
                acc[mi][ni] = __builtin_amdgcn_mfma_f32_16x16x32_bf16(ah[mi], bh[ni], acc[mi][ni], 0, 0, 0);
                acc[mi][ni] = __builtin_amdgcn_mfma_f32_16x16x32_bf16(ah[mi], bl[ni], acc[mi][ni], 0, 0, 0);
                acc[mi][ni] = __builtin_amdgcn_mfma_f32_16x16x32_bf16(al[mi], bh[ni], acc[mi][ni], 0, 0, 0);
            }
        __syncthreads();
    }

    // C/D layout: col = lane&15, row = (lane>>4)*4 + reg
    const int col = lane & 15, rb = (lane >> 4) * 4;
    #pragma unroll
    for (int mi = 0; mi < 4; ++mi) {
        #pragma unroll
        for (int r = 0; r < 4; ++r) {
            int gm = m0 + wm + mi * 16 + rb + r;
            #pragma unroll
            for (int ni = 0; ni < 4; ++ni) {
                int gn = n0 + wn + ni * 16 + col;
                float v = acc[mi][ni][r];
                if (EOP == 0) {
                    C[(size_t)gm * ldc + gn] = v;
                } else if (EOP == 1) {
                    C[(size_t)gm * ldc + gn] = v + E[(size_t)gm * ldE + gn];
                } else if (EOP == 2) {
                    v += E2[gn];
                    v = (v > 20.f) ? v : log1pf(expf(v));
                    C[(size_t)gm * ldc + gn] = v;
                } else if (EOP == 3) {
                    float z2 = E[(size_t)gm * ldE + gn] + v;
                    float s = 1.f / (1.f + __expf(-z2));
                    float g = z2 * s * E2[(size_t)gm * ldE2 + gn];
                    ushort_t h, l;
                    split1(g, h, l);
                    Chi[(size_t)gm * ldc + gn] = h;
                    Clo[(size_t)gm * ldc + gn] = l;
                } else {  // EOP == 4
                    ushort_t h, l;
                    split1(v, h, l);
                    Chi[(size_t)gm * ldc + gn] = h;
                    Clo[(size_t)gm * ldc + gn] = l;
                }
            }
        }
    }
}

// xdbl[m][n] = sum_z Pd[z][m][128+n], n < 96
__global__ __launch_bounds__(256) void reduce_xdbl(
    const float* __restrict__ Pd, float* __restrict__ xdbl)
{
    int idx = blockIdx.x * 256 + threadIdx.x;   // 4096*96
    if (idx >= NTOK * XDBL_N) return;
    int m = idx / XDBL_N, n = idx - m * XDBL_N;
    float s = 0.f;
    #pragma unroll
    for (int zz = 0; zz < 8; ++zz)
        s += Pd[(size_t)zz * NTOK * 128 + (size_t)m * 128 + n];
    xdbl[(size_t)m * XDBL_N + n] = s;
}

// ---------------------------------------------------------------------------
// Chunked selective scan.
// ---------------------------------------------------------------------------
__global__ __launch_bounds__(256) void scan_pass1(
    const float* __restrict__ delta, const float* __restrict__ u,
    const float* __restrict__ Bt, const float* __restrict__ Alog,
    float* __restrict__ Ac, float* __restrict__ Hend)
{
    int d = blockIdx.x * 256 + threadIdx.x;
    int c = blockIdx.y, b = blockIdx.z;
    int t0 = c * CS;
    __shared__ float sB[CS][NST];
    for (int i = threadIdx.x; i < CS * NST; i += 256)
        ((float*)sB)[i] = Bt[(size_t)(b * LSEQ + t0) * NST + i];
    __syncthreads();

    float Avals[NST];
    #pragma unroll
    for (int n = 0; n < NST; ++n) Avals[n] = -__expf(Alog[d * NST + n]);
    float h[NST] = {};
    float P[NST];
    #pragma unroll
    for (int n = 0; n < NST; ++n) P[n] = 1.f;

    const float* dptr = delta + (size_t)(b * LSEQ + t0) * DI + d;
    const float* uptr = u + (size_t)(b * LSEQ + t0) * DI + d;
    for (int tt = 0; tt < CS; ++tt) {
        float dt = dptr[(size_t)tt * DI];
        float ut = uptr[(size_t)tt * DI];
        float wv = dt * ut;
        #pragma unroll
        for (int n = 0; n < NST; ++n) {
            float a = __expf(dt * Avals[n]);
            P[n] *= a;
            h[n] = fmaf(a, h[n], wv * sB[tt][n]);
        }
    }
    size_t o = ((size_t)((b * NCH + c) * DI) + d) * NST;
    #pragma unroll
    for (int n = 0; n < NST; ++n) { Ac[o + n] = P[n]; Hend[o + n] = h[n]; }
}

__global__ __launch_bounds__(256) void scan_pass2(
    float* __restrict__ Ac, const float* __restrict__ Hend)
{
    int idx = blockIdx.x * 256 + threadIdx.x;
    int b = idx / (DI * NST);
    int dn = idx % (DI * NST);
    float h = 0.f;
    for (int c = 0; c < NCH; ++c) {
        size_t o = (size_t)(b * NCH + c) * DI * NST + dn;
        float a = Ac[o];
        float e = Hend[o];
        Ac[o] = h;               // Hin in place
        h = fmaf(a, h, e);
    }
}

__global__ __launch_bounds__(256) void scan_pass3(
    const float* __restrict__ delta, const float* u,
    const float* __restrict__ Bt, const float* __restrict__ Ct,
    const float* __restrict__ Alog, const float* __restrict__ Dp,
    const float* __restrict__ Hin, float* yraw)  // yraw may alias u
{
    int d = blockIdx.x * 256 + threadIdx.x;
    int c = blockIdx.y, b = blockIdx.z;
    int t0 = c * CS;
    __shared__ float sB[CS][NST];
    __shared__ float sC[CS][NST];
    for (int i = threadIdx.x; i < CS * NST; i += 256) {
        ((float*)sB)[i] = Bt[(size_t)(b * LSEQ + t0) * NST + i];
        ((float*)sC)[i] = Ct[(size_t)(b * LSEQ + t0) * NST + i];
    }
    __syncthreads();

    float Avals[NST];
    #pragma unroll
    for (int n = 0; n < NST; ++n) Avals[n] = -__expf(Alog[d * NST + n]);
    float h[NST];
    size_t o = ((size_t)((b * NCH + c) * DI) + d) * NST;
    #pragma unroll
    for (int n = 0; n < NST; ++n) h[n] = Hin[o + n];
    float Dd = Dp[d];

    const float* dptr = delta + (size_t)(b * LSEQ + t0) * DI + d;
    const float* uptr = u + (size_t)(b * LSEQ + t0) * DI + d;
    float* yptr = yraw + (size_t)(b * LSEQ + t0) * DI + d;
    for (int tt = 0; tt < CS; ++tt) {
        float dt = dptr[(size_t)tt * DI];
        float ut = uptr[(size_t)tt * DI];
        float wv = dt * ut;
        float acc = 0.f;
        #pragma unroll
        for (int n = 0; n < NST; ++n) {
            float a = __expf(dt * Avals[n]);
            h[n] = fmaf(a, h[n], wv * sB[tt][n]);
            acc = fmaf(h[n], sC[tt][n], acc);
        }
        yptr[(size_t)tt * DI] = fmaf(Dd, ut, acc);
    }
}

// ---------------------------------------------------------------------------
// Per-token LN -> fp update (in place) -> split(x - y_next) for next u-GEMM
// -> Bt/Ct for token t+1.
// ---------------------------------------------------------------------------
__global__ __launch_bounds__(256) void ln_update_bc(
    const float* __restrict__ yraw, float* __restrict__ ybuf,
    const float* __restrict__ gamma, const float* __restrict__ beta,
    const float* __restrict__ xdbl, const float* __restrict__ Wbc,
    const ushort_t* __restrict__ XHi, const ushort_t* __restrict__ XLo,
    ushort_t* __restrict__ AuHi, ushort_t* __restrict__ AuLo,
    float* __restrict__ Btb, float* __restrict__ Ctb,
    int is_first, int is_final)
{
    int t = blockIdx.x, b = blockIdx.y;
    int tid = threadIdx.x;
    size_t ro = (size_t)(b * LSEQ + t) * DI;
    const float* yr = yraw + ro;
    float* yp = ybuf + ro;

    float s = 0.f, s2 = 0.f;
    float vloc[DI / 256];
    #pragma unroll
    for (int i = 0; i < DI / 256; ++i) {
        float v = yr[tid + i * 256];
        vloc[i] = v; s += v; s2 += v * v;
    }
    #pragma unroll
    for (int off = 32; off >= 1; off >>= 1) {
        s += __shfl_down(s, off, 64);
        s2 += __shfl_down(s2, off, 64);
    }
    __shared__ float rs[4], rs2[4];
    __shared__ float smean, srstd;
    int wid = tid >> 6, lane = tid & 63;
    if (lane == 0) { rs[wid] = s; rs2[wid] = s2; }
    __syncthreads();
    if (tid == 0) {
        float S = rs[0] + rs[1] + rs[2] + rs[3];
        float S2 = rs2[0] + rs2[1] + rs2[2] + rs2[3];
        float m = S / (float)DI;
        float var = S2 / (float)DI - m * m;
        smean = m;
        srstd = rsqrtf(var + EPSF);
    }
    __syncthreads();
    float m = smean, r = srstd;

    __shared__ __align__(16) float srow[DI];
    #pragma unroll
    for (int i = 0; i < DI / 256; ++i) {
        int idx = tid + i * 256;
        float ln = (vloc[i] - m) * r * gamma[idx] + beta[idx];
        float ypv = is_first ? 0.f : yp[idx];
        float yn = is_final ? ln : fmaf(STEPF, ln - ypv, ypv);
        yp[idx] = yn;
        srow[idx] = yn;
        float xv = bf2f(XHi[ro + idx]) + bf2f(XLo[ro + idx]);
        ushort_t h, l;
        split1(xv - yn, h, l);
        AuHi[ro + idx] = h;
        AuLo[ro + idx] = l;
    }
    __syncthreads();

    int colc = tid >> 3, part = tid & 7;
    const float* wv = Wbc + (size_t)colc * DI;
    float partial = 0.f;
    for (int k4 = part * 4; k4 < DI; k4 += 32) {
        float4 w4 = *(const float4*)(wv + k4);
        float4 y4 = *(const float4*)(srow + k4);
        partial += w4.x * y4.x + w4.y * y4.y + w4.z * y4.z + w4.w * y4.w;
    }
    #pragma unroll
    for (int off = 4; off >= 1; off >>= 1) partial += __shfl_down(partial, off, 8);
    __shared__ float sbc[32];
    if (part == 0) sbc[colc] = partial;
    __syncthreads();

    __shared__ float sv[32];
    int tn = t + 1;
    if (tid < 32) {
        float base = (tn < LSEQ) ? xdbl[(size_t)(b * LSEQ + tn) * XDBL_N + DTR + tid] : 0.f;
        sv[tid] = base + sbc[tid];
    }
    __syncthreads();
    if (tid < 32 && tn < LSEQ) {
        int half = tid >> 4;
        float nrm = 0.f;
        #pragma unroll
        for (int j = 0; j < NST; ++j) { float vv = sv[half * NST + j]; nrm += vv * vv; }
        nrm = fmaxf(sqrtf(nrm), EPSF);
        float outv = sv[tid] / nrm;
        float* dst = half ? Ctb : Btb;
        dst[(size_t)(b * LSEQ + tn) * NST + (tid & 15)] = outv;
    }
}

__global__ __launch_bounds__(256) void bc_init(
    const float* __restrict__ xdbl, float* __restrict__ Btb, float* __restrict__ Ctb)
{
    int tok = blockIdx.x * 8 + (threadIdx.x >> 5);
    int i = threadIdx.x & 31;
    float v = xdbl[(size_t)tok * XDBL_N + DTR + i];
    float sq = v * v;
    #pragma unroll
    for (int off = 8; off >= 1; off >>= 1) sq += __shfl_xor(sq, off, 16);
    float nrm = fmaxf(sqrtf(sq), EPSF);
    float outv = v / nrm;
    if (i < 16) Btb[(size_t)tok * NST + i] = outv;
    else        Ctb[(size_t)tok * NST + (i - 16)] = outv;
}

__global__ __launch_bounds__(256) void fill_zero(float* p, size_t n)
{
    size_t i = (size_t)blockIdx.x * blockDim.x + threadIdx.x;
    size_t stride = (size_t)gridDim.x * blockDim.x;
    for (; i < n; i += stride) p[i] = 0.f;
}

// ---------------------------------------------------------------------------
extern "C" void kernel_launch(void* const* d_in, const int* in_sizes, int n_in,
                              void* d_out, int out_size, void* d_ws, size_t ws_size,
                              hipStream_t stream)
{
    const float* hs    = (const float*)d_in[0];
    const float* W_in  = (const float*)d_in[1];
    const float* W_x   = (const float*)d_in[2];
    const float* W_dt  = (const float*)d_in[3];
    const float* b_dt  = (const float*)d_in[4];
    const float* A_log = (const float*)d_in[5];
    const float* W_bc  = (const float*)d_in[6];
    const float* W_zy  = (const float*)d_in[7];
    const float* W_mix = (const float*)d_in[8];
    const float* Dp    = (const float*)d_in[9];
    const float* g_ln  = (const float*)d_in[10];
    const float* b_ln  = (const float*)d_in[11];
    const float* W_out = (const float*)d_in[12];
    float* out = (float*)d_out;

    char* ws = (char*)d_ws;
    size_t off = 0;
    auto alloc = [&](size_t bytes) {
        void* p = (void*)(ws + off);
        off += (bytes + 255) & ~(size_t)255;
        return p;
    };
    float*    z     = (float*)alloc((size_t)NTOK * DI * 4);        // 32 MB
    ushort_t* XHi   = (ushort_t*)alloc((size_t)NTOK * DI * 2);     // 16 MB (later: shift1(y) hi)
    ushort_t* XLo   = (ushort_t*)alloc((size_t)NTOK * DI * 2);     // 16 MB
    float*    delta = (float*)alloc((size_t)NTOK * DI * 4);        // 32 MB (later: Ghi|Glo)
    float*    ubuf  = (float*)alloc((size_t)NTOK * DI * 4);        // 32 MB (prologue: Hs/Win splits)
    float*    yA    = (float*)alloc((size_t)NTOK * DI * 4);        // 32 MB (prologue: xdbl partials)
    ushort_t* AuHi  = (ushort_t*)alloc((size_t)NTOK * DI * 2);     // 16 MB
    ushort_t* AuLo  = (ushort_t*)alloc((size_t)NTOK * DI * 2);     // 16 MB
    ushort_t* WmixHi= (ushort_t*)alloc((size_t)DI * DI * 2);       // 8 MB (later: WzyHi)
    ushort_t* WmixLo= (ushort_t*)alloc((size_t)DI * DI * 2);       // 8 MB (later: WzyLo)
    float*    Ac    = (float*)alloc((size_t)B_SZ * NCH * DI * NST * 4); // 8 MB (later: WoutHi)
    float*    Hend  = (float*)alloc((size_t)B_SZ * NCH * DI * NST * 4); // 8 MB (later: WoutLo)
    float*    xdbl  = (float*)alloc((size_t)NTOK * XDBL_N * 4);    // 1.5 MB
    ushort_t* WxHi  = (ushort_t*)alloc((size_t)128 * DI * 2);
    ushort_t* WxLo  = (ushort_t*)alloc((size_t)128 * DI * 2);
    ushort_t* WdtHi = (ushort_t*)alloc((size_t)DI * DTR * 2);
    ushort_t* WdtLo = (ushort_t*)alloc((size_t)DI * DTR * 2);
    ushort_t* XdHi  = (ushort_t*)alloc((size_t)NTOK * DTR * 2);
    ushort_t* XdLo  = (ushort_t*)alloc((size_t)NTOK * DTR * 2);
    float*    Btb   = (float*)alloc((size_t)NTOK * NST * 4);
    float*    Ctb   = (float*)alloc((size_t)NTOK * NST * 4);

    // prologue aliases
    ushort_t* HsHi  = (ushort_t*)ubuf;
    ushort_t* HsLo  = HsHi + (size_t)NTOK * DM;
    ushort_t* WinHi = HsLo + (size_t)NTOK * DM;
    ushort_t* WinLo = WinHi + (size_t)(2 * DI) * DM;
    float*    Pd    = yA;                           // 8 x 4096 x 128 partials
    // epilogue aliases
    ushort_t* Ghi   = (ushort_t*)delta;
    ushort_t* Glo   = Ghi + (size_t)NTOK * DI;
    ushort_t* WzyHi = WmixHi;
    ushort_t* WzyLo = WmixLo;
    ushort_t* WoutHi= (ushort_t*)Ac;
    ushort_t* WoutLo= (ushort_t*)Hend;
    float*    yraw  = ubuf;

    dim3 blk(256);

    // --- prologue: splits ---
    split_bf16<0><<<4096, blk, 0, stream>>>(hs, HsHi, HsLo, NTOK, DM, DM);
    split_bf16<0><<<4096, blk, 0, stream>>>(W_in, WinHi, WinLo, 2 * DI, DM, DM);
    fill_zero<<<64, blk, 0, stream>>>((float*)WxHi, (size_t)128 * DI / 2);
    fill_zero<<<64, blk, 0, stream>>>((float*)WxLo, (size_t)128 * DI / 2);
    split_bf16<0><<<512, blk, 0, stream>>>(W_x, WxHi, WxLo, XDBL_N, DI, DI);
    split_bf16<0><<<128, blk, 0, stream>>>(W_dt, WdtHi, WdtLo, DI, DTR, DTR);
    split_bf16<0><<<4096, blk, 0, stream>>>(W_mix, WmixHi, WmixLo, DI, DI, DI);

    // x = hs @ W_in[:DI]^T  (split output), z = hs @ W_in[DI:]^T (fp32)
    mfma_gemm<4><<<dim3(DI / 128, NTOK / 128), blk, 0, stream>>>(
        HsHi, HsLo, WinHi, WinLo, nullptr, nullptr, nullptr, XHi, XLo,
        NTOK, DI, DM, 0, 0, DI);
    mfma_gemm<0><<<dim3(DI / 128, NTOK / 128), blk, 0, stream>>>(
        HsHi, HsLo, WinHi + (size_t)DI * DM, WinLo + (size_t)DI * DM,
        nullptr, nullptr, z, nullptr, nullptr, NTOK, DI, DM, 0, 0, DI);

    // xdbl: split-K (8) over K=DI, N padded to 128
    mfma_gemm<0><<<dim3(1, NTOK / 128, 8), blk, 0, stream>>>(
        XHi, XLo, WxHi, WxLo, nullptr, nullptr, Pd, nullptr, nullptr,
        NTOK, 128, DI, 0, 0, 128);
    reduce_xdbl<<<(NTOK * XDBL_N + 255) / 256, blk, 0, stream>>>(Pd, xdbl);

    // delta = softplus(dt_low @ W_dt^T + b_dt)
    split_bf16<0><<<256, blk, 0, stream>>>(xdbl, XdHi, XdLo, NTOK, DTR, XDBL_N);
    mfma_gemm<2><<<dim3(DI / 128, NTOK / 128), blk, 0, stream>>>(
        XdHi, XdLo, WdtHi, WdtLo, nullptr, b_dt, delta, nullptr, nullptr,
        NTOK, DI, DTR, 0, 0, DI);

    bc_init<<<NTOK / 8, 256, 0, stream>>>(xdbl, Btb, Ctb);

    // --- fixed-point loop ---
    for (int it = 0; it <= FP_ITERS; ++it) {
        if (it == 0) {
            // u = x @ W_mix^T   (y = 0)
            mfma_gemm<0><<<dim3(DI / 128, NTOK / 128), blk, 0, stream>>>(
                XHi, XLo, WmixHi, WmixLo, nullptr, nullptr, ubuf, nullptr, nullptr,
                NTOK, DI, DI, 0, 0, DI);
        } else {
            // u = (x - y) @ W_mix^T + y
            mfma_gemm<1><<<dim3(DI / 128, NTOK / 128), blk, 0, stream>>>(
                AuHi, AuLo, WmixHi, WmixLo, yA, nullptr, ubuf, nullptr, nullptr,
                NTOK, DI, DI, DI, 0, DI);
        }
        scan_pass1<<<dim3(DI / 256, NCH, B_SZ), blk, 0, stream>>>(
            delta, ubuf, Btb, A_log, Ac, Hend);
        scan_pass2<<<dim3(B_SZ * DI * NST / 256), blk, 0, stream>>>(Ac, Hend);
        scan_pass3<<<dim3(DI / 256, NCH, B_SZ), blk, 0, stream>>>(
            delta, ubuf, Btb, Ctb, A_log, Dp, Ac, yraw);
        ln_update_bc<<<dim3(LSEQ, B_SZ), blk, 0, stream>>>(
            yraw, yA, g_ln, b_ln, xdbl, W_bc, XHi, XLo, AuHi, AuLo,
            Btb, Ctb, it == 0 ? 1 : 0, it == FP_ITERS ? 1 : 0);
    }

    // --- epilogue ---
    // g = silu(z + shift1(y) @ W_zy^T) * y   (split output into delta buf)
    split_bf16<2><<<8192, blk, 0, stream>>>(yA, (ushort_t*)XHi, (ushort_t*)XLo, NTOK, DI, DI);
    split_bf16<0><<<4096, blk, 0, stream>>>(W_zy, WzyHi, WzyLo, DI, DI, DI);
    mfma_gemm<3><<<dim3(DI / 128, NTOK / 128), blk, 0, stream>>>(
        XHi, XLo, WzyHi, WzyLo, z, yA, nullptr, Ghi, Glo,
        NTOK, DI, DI, DI, DI, DI);

    // out = g @ W_out^T
    split_bf16<0><<<2048, blk, 0, stream>>>(W_out, WoutHi, WoutLo, DM, DI, DI);
    mfma_gemm<0><<<dim3(DM / 128, NTOK / 128), blk, 0, stream>>>(
        Ghi, Glo, WoutHi, WoutLo, nullptr, nullptr, out, nullptr, nullptr,
        NTOK, DM, DI, 0, 0, DM);
}